// Round 15
// baseline (83.816 us; speedup 1.0000x reference)
//
#include <hip/hip_runtime.h>

#define NSTEP 391
#define NB 128

typedef __attribute__((ext_vector_type(8))) short s8v;      // 8 bf16 (4 VGPR)
typedef __attribute__((ext_vector_type(16))) float f32x16;  // MFMA C/D

typedef const __attribute__((address_space(1))) void* gas_ptr;
typedef __attribute__((address_space(3))) void* las_ptr;

union I4S8 { int4 i; s8v v; };
union W4S8 { int w[4]; s8v v; };

#define WAITVM(N) do { asm volatile("s_waitcnt vmcnt(" #N ")" ::: "memory"); \
                       __builtin_amdgcn_sched_barrier(0); } while (0)
#define LGKM0     do { asm volatile("s_waitcnt lgkmcnt(0)" ::: "memory");   \
                       __builtin_amdgcn_sched_barrier(0); } while (0)
#define SBAR      do { __builtin_amdgcn_s_barrier();                        \
                       __builtin_amdgcn_sched_barrier(0); } while (0)

__device__ __forceinline__ int pack_hi(float a, float b) {
    return (__float_as_int(b) & 0xffff0000) | ((unsigned)__float_as_int(a) >> 16);
}
__device__ __forceinline__ float trunc_bf(float a) {
    return __int_as_float(__float_as_int(a) & 0xffff0000);
}
__device__ __forceinline__ int cvtpk(float a, float b) {  // [bf16(b)|bf16(a)] RNE
    int r;
    asm("v_cvt_pk_bf16_f32 %0, %1, %2" : "=v"(r) : "v"(a), "v"(b));
    return r;
}

// ---- prep: BC-form (B = A1, C = A0 - A1; M = B + x0*C since x1 = 1-x0) ----
// (verbatim R12-R14 — proven)
__global__ __launch_bounds__(256) void prep(
    const float* __restrict__ coresL, const float* __restrict__ coresR,
    int* __restrict__ aprep) {
    const int bid = blockIdx.x;            // 0..781
    const int side = bid >= NSTEP;
    const int t = bid - side * NSTEP;
    const float* st = (side ? coresR : coresL) + t * 2048;
    int* out = aprep + (size_t)(side * NSTEP + t) * 2048;
    for (int o = threadIdx.x; o < 2048; o += 256) {
        const int f = o >> 8, lane = (o >> 2) & 63, w = o & 3;
        const int part = f >> 2, p = (f >> 1) & 1, j = f & 1;
        const int h = lane >> 5, c = lane & 31;
        const int k0 = j * 16 + h * 8 + w * 2;
        float e0, e1;
        if (!side) {
            float a00 = st[c * 64 + k0],      a10 = st[c * 64 + 32 + k0];
            float a01 = st[c * 64 + k0 + 1],  a11 = st[c * 64 + 32 + k0 + 1];
            e0 = p ? (a00 - a10) : a10;      // C : B
            e1 = p ? (a01 - a11) : a11;
        } else {
            float a00 = st[k0 * 64 + c],        a10 = st[k0 * 64 + 32 + c];
            float a01 = st[(k0 + 1) * 64 + c],  a11 = st[(k0 + 1) * 64 + 32 + c];
            e0 = p ? (a00 - a10) : a10;
            e1 = p ? (a01 - a11) : a11;
        }
        out[o] = (part == 0) ? pack_hi(e0, e1)
                             : pack_hi(e0 - trunc_bf(e0), e1 - trunc_bf(e1));
    }
}

// Build B-operand fragments from Q (C-layout f32 d[16]).  (proven R7-R14)
__device__ __forceinline__ void bpack(const float* d, bool h0, W4S8& b1h, W4S8& b2h,
                                      W4S8& b1l, W4S8& b2l) {
#if __has_builtin(__builtin_amdgcn_permlane32_swap)
    int hw[8], lw[8];
    #pragma unroll
    for (int q = 0; q < 8; ++q) {
        float e = d[2 * q], o = d[2 * q + 1];
        hw[q] = __builtin_amdgcn_perm(__float_as_uint(o), __float_as_uint(e), 0x07060302u);
        lw[q] = cvtpk(e - trunc_bf(e), o - trunc_bf(o));
    }
    {
        auto r0 = __builtin_amdgcn_permlane32_swap(hw[0], hw[2], false, false);
        b1h.w[0] = r0[0]; b1h.w[2] = r0[1];
        auto r1 = __builtin_amdgcn_permlane32_swap(hw[1], hw[3], false, false);
        b1h.w[1] = r1[0]; b1h.w[3] = r1[1];
        auto r2 = __builtin_amdgcn_permlane32_swap(hw[4], hw[6], false, false);
        b2h.w[0] = r2[0]; b2h.w[2] = r2[1];
        auto r3 = __builtin_amdgcn_permlane32_swap(hw[5], hw[7], false, false);
        b2h.w[1] = r3[0]; b2h.w[3] = r3[1];
        auto r4 = __builtin_amdgcn_permlane32_swap(lw[0], lw[2], false, false);
        b1l.w[0] = r4[0]; b1l.w[2] = r4[1];
        auto r5 = __builtin_amdgcn_permlane32_swap(lw[1], lw[3], false, false);
        b1l.w[1] = r5[0]; b1l.w[3] = r5[1];
        auto r6 = __builtin_amdgcn_permlane32_swap(lw[4], lw[6], false, false);
        b2l.w[0] = r6[0]; b2l.w[2] = r6[1];
        auto r7 = __builtin_amdgcn_permlane32_swap(lw[5], lw[7], false, false);
        b2l.w[1] = r7[0]; b2l.w[3] = r7[1];
    }
    (void)h0;
#else
    float sx[16];
    #pragma unroll
    for (int r = 0; r < 16; ++r) sx[r] = __shfl_xor(d[r], 32);
    float B1[8], B2[8];
    #pragma unroll
    for (int m = 0; m < 4; ++m) {
        B1[m]     = h0 ? d[m]      : sx[4 + m];
        B1[4 + m] = h0 ? sx[m]     : d[4 + m];
        B2[m]     = h0 ? d[8 + m]  : sx[12 + m];
        B2[4 + m] = h0 ? sx[8 + m] : d[12 + m];
    }
    #pragma unroll
    for (int ww = 0; ww < 4; ++ww) {
        b1h.w[ww] = pack_hi(B1[2 * ww], B1[2 * ww + 1]);
        b2h.w[ww] = pack_hi(B2[2 * ww], B2[2 * ww + 1]);
        b1l.w[ww] = cvtpk(B1[2 * ww] - trunc_bf(B1[2 * ww]),
                          B1[2 * ww + 1] - trunc_bf(B1[2 * ww + 1]));
        b2l.w[ww] = cvtpk(B2[2 * ww] - trunc_bf(B2[2 * ww]),
                          B2[2 * ww + 1] - trunc_bf(B2[2 * ww + 1]));
    }
#endif
}

// BC-form step, 4 INDEPENDENT 3-deep chains (dep-latency hiding):
//   a00+a01 = B*Q ; a10+a11 = C*Q ; d = (a00+a01) + u*(a10+a11)
#define MFMA(A, B, C) __builtin_amdgcn_mfma_f32_32x32x16_bf16((A), (B), (C), 0, 0, 0)
__device__ __forceinline__ void mstep(float* d, const I4S8* fr,
                                      const W4S8& b1h, const W4S8& b2h,
                                      const W4S8& b1l, const W4S8& b2l, float u) {
    f32x16 a00 = {}, a01 = {}, a10 = {}, a11 = {};
    // round-robin issue: same-chain spacing = 4 MFMAs (~128 cyc)
    a00 = MFMA(fr[0].v, b1h.v, a00);
    a01 = MFMA(fr[1].v, b2l.v, a01);
    a10 = MFMA(fr[2].v, b1h.v, a10);
    a11 = MFMA(fr[3].v, b2l.v, a11);
    a00 = MFMA(fr[1].v, b2h.v, a00);
    a01 = MFMA(fr[4].v, b1h.v, a01);
    a10 = MFMA(fr[3].v, b2h.v, a10);
    a11 = MFMA(fr[6].v, b1h.v, a11);
    a00 = MFMA(fr[0].v, b1l.v, a00);
    a01 = MFMA(fr[5].v, b2h.v, a01);
    a10 = MFMA(fr[2].v, b1l.v, a10);
    a11 = MFMA(fr[7].v, b2h.v, a11);
    #pragma unroll
    for (int r = 0; r < 16; ++r)
        d[r] = fmaf(u, a10[r] + a11[r], a00[r] + a01[r]);
}

__device__ __forceinline__ void issue_part(const int* tb, int* slot, int lane, int wv) {
    const int f0 = wv * 2;
    __builtin_amdgcn_global_load_lds((gas_ptr)(tb + f0 * 256 + lane * 4),
                                     (las_ptr)(slot + f0 * 256), 16, 0, 0);
    __builtin_amdgcn_global_load_lds((gas_ptr)(tb + (f0 + 1) * 256 + lane * 4),
                                     (las_ptr)(slot + (f0 + 1) * 256), 16, 0, 0);
}

// ---- stage 1: 4-wave block on ONE (side,g) stream, shared 2-slot ring, ----
// ---- 2 b's/wave (R10 base) + split-chain mstep.                        ----
template <int NG>
__global__ __launch_bounds__(256, 4) void stage1(
    const float* __restrict__ x, const int* __restrict__ aprep,
    float* __restrict__ qws) {
    __shared__ int ring[2][2048];           // 16 KB shared tile ring
    __shared__ float xls[8][16];            // per-(wave,b) x0 values
    const int wv = threadIdx.x >> 6;
    const int lane = threadIdx.x & 63;
    constexpr int SPX = 2 * NG / 8;         // streams per XCD
    const int dsp = blockIdx.x;             // 0 .. NG*32-1
    const int xcd = dsp & 7;
    const int s = dsp >> 3;
    const int stream = xcd + 8 * (s % SPX); // 0..2*NG-1
    const int inb = s / SPX;
    const int side = stream >= NG;
    const int g = stream & (NG - 1);
    const int b0 = inb * 8 + wv * 2;        // this wave's two batch elements
    constexpr int qq = NSTEP / NG, rr = NSTEP % NG;
    const int a = g * qq + (g < rr ? g : rr);
    const int len = qq + (g < rr ? 1 : 0);
    const int h = lane >> 5, col = lane & 31;
    const bool h0 = (h == 0);

    {   // stage x0 values: lane-half u loads for batch b0+u
        const int u = lane >> 5, ll = lane & 31;
        if (ll < len) {
            int t = side ? (392 + a + ll) : (a + len - ll);
            xls[wv * 2 + u][ll] = ((const float2*)x + (b0 + u) * 784)[t].x;
        }
    }

    float dA[16], dB[16];
    #pragma unroll
    for (int r = 0; r < 16; ++r) {
        float iv = (((r & 3) + 8 * (r >> 2) + 4 * h) == col) ? 1.0f : 0.0f;  // Q = I
        dA[r] = iv; dB[r] = iv;
    }

    const int* tbase = aprep + (size_t)side * NSTEP * 2048;
    auto taddr = [&](int j) {
        int t = side ? (a + j) : (a + len - 1 - j);
        t = t < 0 ? 0 : (t > NSTEP - 1 ? NSTEP - 1 : t);
        return tbase + (size_t)t * 2048;
    };

    issue_part(taddr(0), ring[0], lane, wv);
    issue_part(taddr(1), ring[1], lane, wv);

    for (int j = 0; j < len; ++j) {
        int* slot = ring[j & 1];
        W4S8 p1h, p2h, p1l, p2l, q1h, q2h, q1l, q2l;
        bpack(dA, h0, p1h, p2h, p1l, p2l);  // overlaps in-flight loads
        bpack(dB, h0, q1h, q2h, q1l, q2l);
        WAITVM(2);                           // own parts of tile j landed
        SBAR;                                // tile j fully landed
        I4S8 fr[8];
        #pragma unroll
        for (int f = 0; f < 8; ++f)
            fr[f].i = *(const int4*)(slot + f * 256 + lane * 4);
        LGKM0;                               // own reads of slot done
        SBAR;                                // all waves read -> slot free
        issue_part(taddr(j + 2), slot, lane, wv);   // loads fly under mstep
        __builtin_amdgcn_s_setprio(1);
        mstep(dA, fr, p1h, p2h, p1l, p2l, xls[wv * 2][j]);
        mstep(dB, fr, q1h, q2h, q1l, q2l, xls[wv * 2 + 1][j]);
        __builtin_amdgcn_s_setprio(0);
    }
    WAITVM(0);   // drain clamp prefetches before LDS can be reallocated

    // qws task = (side*NB + b)*NG + g
    float4* q0 = (float4*)(qws + ((size_t)(side * NB + b0) * NG + g) * 1024 + lane * 16);
    float4* q1 = (float4*)(qws + ((size_t)(side * NB + b0 + 1) * NG + g) * 1024 + lane * 16);
    q0[0] = make_float4(dA[0], dA[1], dA[2], dA[3]);
    q0[1] = make_float4(dA[4], dA[5], dA[6], dA[7]);
    q0[2] = make_float4(dA[8], dA[9], dA[10], dA[11]);
    q0[3] = make_float4(dA[12], dA[13], dA[14], dA[15]);
    q1[0] = make_float4(dB[0], dB[1], dB[2], dB[3]);
    q1[1] = make_float4(dB[4], dB[5], dB[6], dB[7]);
    q1[2] = make_float4(dB[8], dB[9], dB[10], dB[11]);
    q1[3] = make_float4(dB[12], dB[13], dB[14], dB[15]);
}

// ---- stage 2 (fused with final): one wave per b, both sides as ILP pair ----
template <int NG>
__global__ __launch_bounds__(64) void stage2f(
    const float* __restrict__ x, const float* __restrict__ a0,
    const float* __restrict__ aend, const float* __restrict__ qws,
    const float* __restrict__ mid, float* __restrict__ out) {
    __shared__ float ring[2][2048];         // 2 slots x (2 sides x 1024 f32)
    const int b = blockIdx.x;
    const int lane = threadIdx.x;
    const int c = lane & 31;
    const int j = lane >> 5;
    const float2* xb = (const float2*)x + b * 784;
    float2 x0 = xb[0], xe = xb[783];
    float v0 = fmaf(a0[c * 2], x0.x, a0[c * 2 + 1] * x0.y);
    float v1 = fmaf(aend[c * 2], xe.x, aend[c * 2 + 1] * xe.y);

    auto issue = [&](int i, float* slot) {
        int ic = i < NG - 1 ? i : NG - 1;
        const float* t0 = qws + ((size_t)b * NG + ic) * 1024;
        const float* t1 = qws + ((size_t)(NB + b) * NG + (NG - 1 - ic)) * 1024;
        #pragma unroll
        for (int u = 0; u < 4; ++u) {
            __builtin_amdgcn_global_load_lds((gas_ptr)(t0 + u * 256 + lane * 4),
                                             (las_ptr)(slot + u * 256), 16, 0, 0);
            __builtin_amdgcn_global_load_lds((gas_ptr)(t1 + u * 256 + lane * 4),
                                             (las_ptr)(slot + 1024 + u * 256), 16, 0, 0);
        }
    };
    issue(0, ring[0]);
    issue(1, ring[1]);

    for (int i = 0; i < NG; ++i) {
        float* slot = ring[i & 1];
        WAITVM(8);                           // tile i landed (i+1 in flight)
        float q0[16], q1[16];
        #pragma unroll
        for (int u = 0; u < 4; ++u) {
            float4 t4 = *(const float4*)(slot + lane * 16 + u * 4);
            q0[4 * u] = t4.x; q0[4 * u + 1] = t4.y; q0[4 * u + 2] = t4.z; q0[4 * u + 3] = t4.w;
            float4 t5 = *(const float4*)(slot + 1024 + lane * 16 + u * 4);
            q1[4 * u] = t5.x; q1[4 * u + 1] = t5.y; q1[4 * u + 2] = t5.z; q1[4 * u + 3] = t5.w;
        }
        LGKM0;                               // reads done -> slot reusable
        issue(i + 2, slot);
        float s0 = 0.f, s1 = 0.f, s2 = 0.f, s3 = 0.f;
        float u0 = 0.f, u1 = 0.f, u2 = 0.f, u3 = 0.f;
        #pragma unroll
        for (int r = 0; r < 16; r += 4) {
            const int base = 8 * (r >> 2) + 4 * j;
            s0 = fmaf(__shfl(v0, base + 0, 64), q0[r + 0], s0);
            u0 = fmaf(__shfl(v1, base + 0, 64), q1[r + 0], u0);
            s1 = fmaf(__shfl(v0, base + 1, 64), q0[r + 1], s1);
            u1 = fmaf(__shfl(v1, base + 1, 64), q1[r + 1], u1);
            s2 = fmaf(__shfl(v0, base + 2, 64), q0[r + 2], s2);
            u2 = fmaf(__shfl(v1, base + 2, 64), q1[r + 2], u2);
            s3 = fmaf(__shfl(v0, base + 3, 64), q0[r + 3], s3);
            u3 = fmaf(__shfl(v1, base + 3, 64), q1[r + 3], u3);
        }
        float sv = (s0 + s1) + (s2 + s3);
        float uv = (u0 + u1) + (u2 + u3);
        sv += __shfl_xor(sv, 32);
        uv += __shfl_xor(uv, 32);
        v0 = sv; v1 = uv;
    }
    WAITVM(0);   // drain clamp prefetches before LDS can be reallocated

    float pa = v0 * v1;
    #pragma unroll
    for (int cc = 0; cc < 10; ++cc) {
        float s = pa * mid[c * 320 + cc * 32 + c];   // mid_diag[a,cc] = core_mid[a,cc,a]
        s += __shfl_xor(s, 16, 32);
        s += __shfl_xor(s, 8, 32);
        s += __shfl_xor(s, 4, 32);
        s += __shfl_xor(s, 2, 32);
        s += __shfl_xor(s, 1, 32);
        if (lane == 0) out[b * 10 + cc] = s;
    }
}

extern "C" void kernel_launch(void* const* d_in, const int* in_sizes, int n_in,
                              void* d_out, int out_size, void* d_ws, size_t ws_size,
                              hipStream_t stream) {
    const float* x      = (const float*)d_in[0];
    const float* a0     = (const float*)d_in[1];
    const float* coresL = (const float*)d_in[2];
    const float* mid    = (const float*)d_in[3];
    const float* coresR = (const float*)d_in[4];
    const float* aend   = (const float*)d_in[5];

    int*   aprep = (int*)d_ws;                           // 2*391*2048 ints = 6.4 MB
    float* qws   = (float*)d_ws + 2 * NSTEP * 2048;
    float* out   = (float*)d_out;

    const size_t base = (size_t)(2 * NSTEP * 2048) * 4;
    const size_t need32 = base + (size_t)2 * NB * 32 * 1024 * 4;  // ~40 MB

    prep<<<dim3(2 * NSTEP), dim3(256), 0, stream>>>(coresL, coresR, aprep);
    if (ws_size >= need32) {
        stage1<32><<<dim3(1024), dim3(256), 0, stream>>>(x, aprep, qws);
        stage2f<32><<<dim3(NB), dim3(64), 0, stream>>>(x, a0, aend, qws, mid, out);
    } else {
        stage1<16><<<dim3(512), dim3(256), 0, stream>>>(x, aprep, qws);
        stage2f<16><<<dim3(NB), dim3(64), 0, stream>>>(x, a0, aend, qws, mid, out);
    }
}

// Round 16
// 71.631 us; speedup vs baseline: 1.1701x; 1.1701x over previous
//
#include <hip/hip_runtime.h>

#define NSTEP 391
#define NB 128

typedef __attribute__((ext_vector_type(8))) short s8v;      // 8 bf16 (4 VGPR)
typedef __attribute__((ext_vector_type(16))) float f32x16;  // MFMA C/D

typedef const __attribute__((address_space(1))) void* gas_ptr;
typedef __attribute__((address_space(3))) void* las_ptr;

union I4S8 { int4 i; s8v v; };
union W4S8 { int w[4]; s8v v; };

#define WAITVM(N) do { asm volatile("s_waitcnt vmcnt(" #N ")" ::: "memory"); \
                       __builtin_amdgcn_sched_barrier(0); } while (0)
#define LGKM0     do { asm volatile("s_waitcnt lgkmcnt(0)" ::: "memory");   \
                       __builtin_amdgcn_sched_barrier(0); } while (0)
#define SBAR      do { __builtin_amdgcn_s_barrier();                        \
                       __builtin_amdgcn_sched_barrier(0); } while (0)

__device__ __forceinline__ int pack_hi(float a, float b) {
    return (__float_as_int(b) & 0xffff0000) | ((unsigned)__float_as_int(a) >> 16);
}
__device__ __forceinline__ float trunc_bf(float a) {
    return __int_as_float(__float_as_int(a) & 0xffff0000);
}
__device__ __forceinline__ int cvtpk(float a, float b) {  // [bf16(b)|bf16(a)] RNE
    int r;
    asm("v_cvt_pk_bf16_f32 %0, %1, %2" : "=v"(r) : "v"(a), "v"(b));
    return r;
}

// ---- prep: BC-form (B = A1, C = A0 - A1; M = B + x0*C since x1 = 1-x0) ----
// (verbatim R12-R15 — proven)
__global__ __launch_bounds__(256) void prep(
    const float* __restrict__ coresL, const float* __restrict__ coresR,
    int* __restrict__ aprep) {
    const int bid = blockIdx.x;            // 0..781
    const int side = bid >= NSTEP;
    const int t = bid - side * NSTEP;
    const float* st = (side ? coresR : coresL) + t * 2048;
    int* out = aprep + (size_t)(side * NSTEP + t) * 2048;
    for (int o = threadIdx.x; o < 2048; o += 256) {
        const int f = o >> 8, lane = (o >> 2) & 63, w = o & 3;
        const int part = f >> 2, p = (f >> 1) & 1, j = f & 1;
        const int h = lane >> 5, c = lane & 31;
        const int k0 = j * 16 + h * 8 + w * 2;
        float e0, e1;
        if (!side) {
            float a00 = st[c * 64 + k0],      a10 = st[c * 64 + 32 + k0];
            float a01 = st[c * 64 + k0 + 1],  a11 = st[c * 64 + 32 + k0 + 1];
            e0 = p ? (a00 - a10) : a10;      // C : B
            e1 = p ? (a01 - a11) : a11;
        } else {
            float a00 = st[k0 * 64 + c],        a10 = st[k0 * 64 + 32 + c];
            float a01 = st[(k0 + 1) * 64 + c],  a11 = st[(k0 + 1) * 64 + 32 + c];
            e0 = p ? (a00 - a10) : a10;
            e1 = p ? (a01 - a11) : a11;
        }
        out[o] = (part == 0) ? pack_hi(e0, e1)
                             : pack_hi(e0 - trunc_bf(e0), e1 - trunc_bf(e1));
    }
}

// Build B-operand fragments from Q (C-layout f32 d[16]).  (proven R7-R15)
__device__ __forceinline__ void bpack(const float* d, bool h0, W4S8& b1h, W4S8& b2h,
                                      W4S8& b1l, W4S8& b2l) {
#if __has_builtin(__builtin_amdgcn_permlane32_swap)
    int hw[8], lw[8];
    #pragma unroll
    for (int q = 0; q < 8; ++q) {
        float e = d[2 * q], o = d[2 * q + 1];
        hw[q] = __builtin_amdgcn_perm(__float_as_uint(o), __float_as_uint(e), 0x07060302u);
        lw[q] = cvtpk(e - trunc_bf(e), o - trunc_bf(o));
    }
    {
        auto r0 = __builtin_amdgcn_permlane32_swap(hw[0], hw[2], false, false);
        b1h.w[0] = r0[0]; b1h.w[2] = r0[1];
        auto r1 = __builtin_amdgcn_permlane32_swap(hw[1], hw[3], false, false);
        b1h.w[1] = r1[0]; b1h.w[3] = r1[1];
        auto r2 = __builtin_amdgcn_permlane32_swap(hw[4], hw[6], false, false);
        b2h.w[0] = r2[0]; b2h.w[2] = r2[1];
        auto r3 = __builtin_amdgcn_permlane32_swap(hw[5], hw[7], false, false);
        b2h.w[1] = r3[0]; b2h.w[3] = r3[1];
        auto r4 = __builtin_amdgcn_permlane32_swap(lw[0], lw[2], false, false);
        b1l.w[0] = r4[0]; b1l.w[2] = r4[1];
        auto r5 = __builtin_amdgcn_permlane32_swap(lw[1], lw[3], false, false);
        b1l.w[1] = r5[0]; b1l.w[3] = r5[1];
        auto r6 = __builtin_amdgcn_permlane32_swap(lw[4], lw[6], false, false);
        b2l.w[0] = r6[0]; b2l.w[2] = r6[1];
        auto r7 = __builtin_amdgcn_permlane32_swap(lw[5], lw[7], false, false);
        b2l.w[1] = r7[0]; b2l.w[3] = r7[1];
    }
    (void)h0;
#else
    float sx[16];
    #pragma unroll
    for (int r = 0; r < 16; ++r) sx[r] = __shfl_xor(d[r], 32);
    float B1[8], B2[8];
    #pragma unroll
    for (int m = 0; m < 4; ++m) {
        B1[m]     = h0 ? d[m]      : sx[4 + m];
        B1[4 + m] = h0 ? sx[m]     : d[4 + m];
        B2[m]     = h0 ? d[8 + m]  : sx[12 + m];
        B2[4 + m] = h0 ? sx[8 + m] : d[12 + m];
    }
    #pragma unroll
    for (int ww = 0; ww < 4; ++ww) {
        b1h.w[ww] = pack_hi(B1[2 * ww], B1[2 * ww + 1]);
        b2h.w[ww] = pack_hi(B2[2 * ww], B2[2 * ww + 1]);
        b1l.w[ww] = cvtpk(B1[2 * ww] - trunc_bf(B1[2 * ww]),
                          B1[2 * ww + 1] - trunc_bf(B1[2 * ww + 1]));
        b2l.w[ww] = cvtpk(B2[2 * ww] - trunc_bf(B2[2 * ww]),
                          B2[2 * ww + 1] - trunc_bf(B2[2 * ww + 1]));
    }
#endif
}

// BC-form step (2 chains, R14-proven no-spill): acc0 = B*Q, acc1 = C*Q ;
// d = acc0 + u*acc1  (u = x0 ; x1 = 1-x0 by construction)
__device__ __forceinline__ void mstep(float* d, const I4S8* fr,
                                      const W4S8& b1h, const W4S8& b2h,
                                      const W4S8& b1l, const W4S8& b2l, float u) {
    f32x16 acc0 = {}; f32x16 acc1 = {};
    acc0 = __builtin_amdgcn_mfma_f32_32x32x16_bf16(fr[0].v, b1h.v, acc0, 0, 0, 0);
    acc1 = __builtin_amdgcn_mfma_f32_32x32x16_bf16(fr[2].v, b1h.v, acc1, 0, 0, 0);
    acc0 = __builtin_amdgcn_mfma_f32_32x32x16_bf16(fr[1].v, b2h.v, acc0, 0, 0, 0);
    acc1 = __builtin_amdgcn_mfma_f32_32x32x16_bf16(fr[3].v, b2h.v, acc1, 0, 0, 0);
    acc0 = __builtin_amdgcn_mfma_f32_32x32x16_bf16(fr[0].v, b1l.v, acc0, 0, 0, 0);
    acc1 = __builtin_amdgcn_mfma_f32_32x32x16_bf16(fr[2].v, b1l.v, acc1, 0, 0, 0);
    acc0 = __builtin_amdgcn_mfma_f32_32x32x16_bf16(fr[1].v, b2l.v, acc0, 0, 0, 0);
    acc1 = __builtin_amdgcn_mfma_f32_32x32x16_bf16(fr[3].v, b2l.v, acc1, 0, 0, 0);
    acc0 = __builtin_amdgcn_mfma_f32_32x32x16_bf16(fr[4].v, b1h.v, acc0, 0, 0, 0);
    acc1 = __builtin_amdgcn_mfma_f32_32x32x16_bf16(fr[6].v, b1h.v, acc1, 0, 0, 0);
    acc0 = __builtin_amdgcn_mfma_f32_32x32x16_bf16(fr[5].v, b2h.v, acc0, 0, 0, 0);
    acc1 = __builtin_amdgcn_mfma_f32_32x32x16_bf16(fr[7].v, b2h.v, acc1, 0, 0, 0);
    #pragma unroll
    for (int r = 0; r < 16; ++r) d[r] = fmaf(u, acc1[r], acc0[r]);
}

__device__ __forceinline__ void issue_part(const int* tb, int* slot, int lane, int wv) {
    const int f0 = wv * 2;
    __builtin_amdgcn_global_load_lds((gas_ptr)(tb + f0 * 256 + lane * 4),
                                     (las_ptr)(slot + f0 * 256), 16, 0, 0);
    __builtin_amdgcn_global_load_lds((gas_ptr)(tb + (f0 + 1) * 256 + lane * 4),
                                     (las_ptr)(slot + (f0 + 1) * 256), 16, 0, 0);
}

// ---- stage 1: R8-proven structure (4 waves on ONE (side,g) stream, one ----
// ---- b per wave, shared 2-slot ring) + BC-form + CORRECTED phase skew. ----
// Co-resident blocks on a CU are {d, d+256, d+512, d+768} (8 XCD x 32 CU
// round-robin) -> skew class must be (dsp>>8)&3, not (dsp>>3)&3 (R14 bug).
__global__ __launch_bounds__(256, 4) void stage1(
    const float* __restrict__ x, const int* __restrict__ aprep,
    float* __restrict__ qws) {
    __shared__ int ring[2][2048];           // 16 KB shared tile ring
    __shared__ float xls[4][28];            // per-wave x0 values
    const int wv = threadIdx.x >> 6;
    const int lane = threadIdx.x & 63;
    const int dsp = blockIdx.x;             // 0..1023
    const int xcd = dsp & 7;
    const int s = dsp >> 3;                 // 0..127
    const int stream = xcd + 8 * (s & 3);   // 0..31
    const int inb = s >> 2;                 // 0..31
    const int side = stream >> 4;
    const int g = stream & 15;
    const int b = inb * 4 + wv;             // this wave's batch element
    const int a = g * 24 + (g < 7 ? g : 7);
    const int len = 24 + (g < 7 ? 1 : 0);
    const int h = lane >> 5, col = lane & 31;
    const bool h0 = (h == 0);

    const float2* xb2 = (const float2*)x + b * 784;
    if (lane < len) {
        int t = side ? (392 + a + lane) : (a + len - lane);
        xls[wv][lane] = xb2[t].x;
    }

    // quarter-step phase skew across the 4 co-resident generations
    switch ((dsp >> 8) & 3) {
        case 1: asm volatile("s_sleep 18"); break;   // ~1150 cyc
        case 2: asm volatile("s_sleep 36"); break;   // ~2300 cyc
        case 3: asm volatile("s_sleep 54"); break;   // ~3450 cyc
        default: break;
    }

    float d0[16];
    #pragma unroll
    for (int r = 0; r < 16; ++r)
        d0[r] = (((r & 3) + 8 * (r >> 2) + 4 * h) == col) ? 1.0f : 0.0f;  // Q = I

    const int* tbase = aprep + (size_t)side * NSTEP * 2048;
    auto taddr = [&](int j) {
        int t = side ? (a + j) : (a + len - 1 - j);
        t = t < 0 ? 0 : (t > NSTEP - 1 ? NSTEP - 1 : t);
        return tbase + (size_t)t * 2048;
    };

    issue_part(taddr(0), ring[0], lane, wv);
    issue_part(taddr(1), ring[1], lane, wv);

    for (int j = 0; j < len; ++j) {
        int* slot = ring[j & 1];
        W4S8 b1h, b2h, b1l, b2l;
        bpack(d0, h0, b1h, b2h, b1l, b2l);  // overlaps in-flight loads
        WAITVM(2);                           // own parts of tile j landed
        SBAR;                                // tile j fully landed
        I4S8 fr[8];
        #pragma unroll
        for (int f = 0; f < 8; ++f)
            fr[f].i = *(const int4*)(slot + f * 256 + lane * 4);
        LGKM0;                               // own reads of slot done
        SBAR;                                // all waves read -> slot free
        issue_part(taddr(j + 2), slot, lane, wv);   // loads fly under mstep
        __builtin_amdgcn_s_setprio(1);
        mstep(d0, fr, b1h, b2h, b1l, b2l, xls[wv][j]);
        __builtin_amdgcn_s_setprio(0);
    }
    WAITVM(0);   // drain clamp prefetches before LDS can be reallocated

    // qws task = (side*NB + b)*16 + g
    float4* q0 = (float4*)(qws + ((size_t)(side * NB + b) * 16 + g) * 1024 + lane * 16);
    q0[0] = make_float4(d0[0], d0[1], d0[2], d0[3]);
    q0[1] = make_float4(d0[4], d0[5], d0[6], d0[7]);
    q0[2] = make_float4(d0[8], d0[9], d0[10], d0[11]);
    q0[3] = make_float4(d0[12], d0[13], d0[14], d0[15]);
}

// ---- stage 2 (fused with final): one wave per b, both sides as ILP pair ----
// (R9/R10-proven, NG = 16)
__global__ __launch_bounds__(64) void stage2f(
    const float* __restrict__ x, const float* __restrict__ a0,
    const float* __restrict__ aend, const float* __restrict__ qws,
    const float* __restrict__ mid, float* __restrict__ out) {
    constexpr int NG = 16;
    __shared__ float ring[2][2048];         // 2 slots x (2 sides x 1024 f32)
    const int b = blockIdx.x;
    const int lane = threadIdx.x;
    const int c = lane & 31;
    const int j = lane >> 5;
    const float2* xb = (const float2*)x + b * 784;
    float2 x0 = xb[0], xe = xb[783];
    float v0 = fmaf(a0[c * 2], x0.x, a0[c * 2 + 1] * x0.y);
    float v1 = fmaf(aend[c * 2], xe.x, aend[c * 2 + 1] * xe.y);

    auto issue = [&](int i, float* slot) {
        int ic = i < NG - 1 ? i : NG - 1;
        const float* t0 = qws + ((size_t)b * NG + ic) * 1024;
        const float* t1 = qws + ((size_t)(NB + b) * NG + (NG - 1 - ic)) * 1024;
        #pragma unroll
        for (int u = 0; u < 4; ++u) {
            __builtin_amdgcn_global_load_lds((gas_ptr)(t0 + u * 256 + lane * 4),
                                             (las_ptr)(slot + u * 256), 16, 0, 0);
            __builtin_amdgcn_global_load_lds((gas_ptr)(t1 + u * 256 + lane * 4),
                                             (las_ptr)(slot + 1024 + u * 256), 16, 0, 0);
        }
    };
    issue(0, ring[0]);
    issue(1, ring[1]);

    for (int i = 0; i < NG; ++i) {
        float* slot = ring[i & 1];
        WAITVM(8);                           // tile i landed (i+1 in flight)
        float q0[16], q1[16];
        #pragma unroll
        for (int u = 0; u < 4; ++u) {
            float4 t4 = *(const float4*)(slot + lane * 16 + u * 4);
            q0[4 * u] = t4.x; q0[4 * u + 1] = t4.y; q0[4 * u + 2] = t4.z; q0[4 * u + 3] = t4.w;
            float4 t5 = *(const float4*)(slot + 1024 + lane * 16 + u * 4);
            q1[4 * u] = t5.x; q1[4 * u + 1] = t5.y; q1[4 * u + 2] = t5.z; q1[4 * u + 3] = t5.w;
        }
        LGKM0;                               // reads done -> slot reusable
        issue(i + 2, slot);
        float s0 = 0.f, s1 = 0.f, s2 = 0.f, s3 = 0.f;
        float u0 = 0.f, u1 = 0.f, u2 = 0.f, u3 = 0.f;
        #pragma unroll
        for (int r = 0; r < 16; r += 4) {
            const int base = 8 * (r >> 2) + 4 * j;
            s0 = fmaf(__shfl(v0, base + 0, 64), q0[r + 0], s0);
            u0 = fmaf(__shfl(v1, base + 0, 64), q1[r + 0], u0);
            s1 = fmaf(__shfl(v0, base + 1, 64), q0[r + 1], s1);
            u1 = fmaf(__shfl(v1, base + 1, 64), q1[r + 1], u1);
            s2 = fmaf(__shfl(v0, base + 2, 64), q0[r + 2], s2);
            u2 = fmaf(__shfl(v1, base + 2, 64), q1[r + 2], u2);
            s3 = fmaf(__shfl(v0, base + 3, 64), q0[r + 3], s3);
            u3 = fmaf(__shfl(v1, base + 3, 64), q1[r + 3], u3);
        }
        float sv = (s0 + s1) + (s2 + s3);
        float uv = (u0 + u1) + (u2 + u3);
        sv += __shfl_xor(sv, 32);
        uv += __shfl_xor(uv, 32);
        v0 = sv; v1 = uv;
    }
    WAITVM(0);   // drain clamp prefetches before LDS can be reallocated

    float pa = v0 * v1;
    #pragma unroll
    for (int cc = 0; cc < 10; ++cc) {
        float s = pa * mid[c * 320 + cc * 32 + c];   // mid_diag[a,cc] = core_mid[a,cc,a]
        s += __shfl_xor(s, 16, 32);
        s += __shfl_xor(s, 8, 32);
        s += __shfl_xor(s, 4, 32);
        s += __shfl_xor(s, 2, 32);
        s += __shfl_xor(s, 1, 32);
        if (lane == 0) out[b * 10 + cc] = s;
    }
}

extern "C" void kernel_launch(void* const* d_in, const int* in_sizes, int n_in,
                              void* d_out, int out_size, void* d_ws, size_t ws_size,
                              hipStream_t stream) {
    const float* x      = (const float*)d_in[0];
    const float* a0     = (const float*)d_in[1];
    const float* coresL = (const float*)d_in[2];
    const float* mid    = (const float*)d_in[3];
    const float* coresR = (const float*)d_in[4];
    const float* aend   = (const float*)d_in[5];

    int*   aprep = (int*)d_ws;                           // 2*391*2048 ints = 6.4 MB
    float* qws   = (float*)d_ws + 2 * NSTEP * 2048;      // 2*128*16*1024 f32 = 16.8 MB
    float* out   = (float*)d_out;

    prep<<<dim3(2 * NSTEP), dim3(256), 0, stream>>>(coresL, coresR, aprep);
    stage1<<<dim3(1024), dim3(256), 0, stream>>>(x, aprep, qws);
    stage2f<<<dim3(NB), dim3(64), 0, stream>>>(x, a0, aend, qws, mid, out);
}